// Round 6
// baseline (79.194 us; speedup 1.0000x reference)
//
#include <hip/hip_runtime.h>

typedef float v2f __attribute__((ext_vector_type(2)));

constexpr int IN_D = 18, W_HID = 10, N_HID = 19;
constexpr float SLOPE = 0.1f;

// LDS layout (floats):
//   [0      .. 200)  W0 padded: 10 rows x 20  -> row r: [w(r,0..17), b0[r], pad]
//   [200    .. 2480) Ws padded: 19 layers x 10 rows x 12 -> row: [w(j,0..9), bs[l][j], pad]
//   [2480   .. 2492) Wf padded: [wf0..wf9, bf, pad]
constexpr int L0_BASE = 0, LH_BASE = 200, LF_BASE = 2480, LDS_FLOATS = 2492;

__device__ __forceinline__ v2f splat(float s) { v2f v; v[0] = s; v[1] = s; return v; }

__device__ __forceinline__ v2f lrelu2(v2f x) {
    return __builtin_elementwise_max(x, x * splat(SLOPE));   // pk_mul + pk_max
}

// One 10->10 layer from LDS rows of 12 floats: [w0..w9, bias, pad]
__device__ __forceinline__ void layer10_lds(const v2f* __restrict__ in, v2f* __restrict__ outv,
                                            const float* __restrict__ lbase) {
    #pragma unroll
    for (int j = 0; j < W_HID; ++j) {
        const float4* row = reinterpret_cast<const float4*>(lbase + j * 12);
        float4 wa = row[0], wb = row[1], wc = row[2];   // 3x ds_read_b128 (uniform addr)
        v2f acc = splat(wc.z);                          // bias
        acc = __builtin_elementwise_fma(in[0], splat(wa.x), acc);
        acc = __builtin_elementwise_fma(in[1], splat(wa.y), acc);
        acc = __builtin_elementwise_fma(in[2], splat(wa.z), acc);
        acc = __builtin_elementwise_fma(in[3], splat(wa.w), acc);
        acc = __builtin_elementwise_fma(in[4], splat(wb.x), acc);
        acc = __builtin_elementwise_fma(in[5], splat(wb.y), acc);
        acc = __builtin_elementwise_fma(in[6], splat(wb.z), acc);
        acc = __builtin_elementwise_fma(in[7], splat(wb.w), acc);
        acc = __builtin_elementwise_fma(in[8], splat(wc.x), acc);
        acc = __builtin_elementwise_fma(in[9], splat(wc.y), acc);
        outv[j] = lrelu2(acc);
    }
}

// 2 samples/thread, rolled hidden loop (I$-resident), weights staged in LDS (no scalar loads in loop).
__global__ __launch_bounds__(256, 8) void critic_pk2_lds(
    const float* __restrict__ state, const float* __restrict__ action,
    const float* __restrict__ W0, const float* __restrict__ bias0,
    const float* __restrict__ Ws, const float* __restrict__ bs,
    const float* __restrict__ Wf, const float* __restrict__ bf,
    float* __restrict__ out, int B)
{
    __shared__ float4 lds4[(LDS_FLOATS + 3) / 4];
    float* lds = reinterpret_cast<float*>(lds4);

    const int tid = threadIdx.x;

    // ---- stage all weights into LDS (one-time per block) ----
    if (tid < 180) { int r = tid / 18, c = tid % 18; lds[L0_BASE + r * 20 + c] = W0[tid]; }
    if (tid >= 192 && tid < 202) { int r = tid - 192; lds[L0_BASE + r * 20 + 18] = bias0[r]; }
    #pragma unroll
    for (int k = 0; k < 8; ++k) {
        int idx = tid + 256 * k;                     // 1900 weight elements
        if (idx < 1900) {
            int l = idx / 100, rem = idx % 100;
            int r = rem / 10, c = rem % 10;
            lds[LH_BASE + l * 120 + r * 12 + c] = Ws[idx];
        }
    }
    if (tid < 190) { int l = tid / 10, r = tid % 10; lds[LH_BASE + l * 120 + r * 12 + 10] = bs[tid]; }
    if (tid >= 208 && tid < 218) lds[LF_BASE + (tid - 208)] = Wf[tid - 208];
    if (tid == 224) lds[LF_BASE + 10] = bf[0];
    __syncthreads();

    const int t = blockIdx.x * blockDim.x + tid;
    if (t * 2 < B) {
        // ---- 2 state rows (96 B, 16B-aligned) ----
        float Sf[24];
        {
            const float4* s4 = reinterpret_cast<const float4*>(state) + (size_t)t * 6;
            #pragma unroll
            for (int r = 0; r < 6; ++r) {
                float4 v = s4[r];
                Sf[4*r] = v.x; Sf[4*r+1] = v.y; Sf[4*r+2] = v.z; Sf[4*r+3] = v.w;
            }
        }
        // ---- 2 action rows (48 B, 16B-aligned) ----
        float Af[12];
        {
            const float4* a4 = reinterpret_cast<const float4*>(action) + (size_t)t * 3;
            #pragma unroll
            for (int r = 0; r < 3; ++r) {
                float4 v = a4[r];
                Af[4*r] = v.x; Af[4*r+1] = v.y; Af[4*r+2] = v.z; Af[4*r+3] = v.w;
            }
        }

        v2f x[IN_D];
        #pragma unroll
        for (int k = 0; k < 12; ++k) { v2f v; v[0] = Sf[k]; v[1] = Sf[12 + k]; x[k] = v; }
        #pragma unroll
        for (int k = 0; k < 6; ++k)  { v2f v; v[0] = Af[k]; v[1] = Af[6 + k];  x[12 + k] = v; }

        // ---- layer 0: 18 -> 10 (rows of 20 floats: 5x b128) ----
        v2f h[W_HID], g[W_HID];
        #pragma unroll
        for (int j = 0; j < W_HID; ++j) {
            const float4* row = reinterpret_cast<const float4*>(lds + L0_BASE + j * 20);
            float4 wa = row[0], wb = row[1], wc = row[2], wd = row[3], we = row[4];
            v2f acc = splat(we.z);    // b0[j]
            acc = __builtin_elementwise_fma(x[0],  splat(wa.x), acc);
            acc = __builtin_elementwise_fma(x[1],  splat(wa.y), acc);
            acc = __builtin_elementwise_fma(x[2],  splat(wa.z), acc);
            acc = __builtin_elementwise_fma(x[3],  splat(wa.w), acc);
            acc = __builtin_elementwise_fma(x[4],  splat(wb.x), acc);
            acc = __builtin_elementwise_fma(x[5],  splat(wb.y), acc);
            acc = __builtin_elementwise_fma(x[6],  splat(wb.z), acc);
            acc = __builtin_elementwise_fma(x[7],  splat(wb.w), acc);
            acc = __builtin_elementwise_fma(x[8],  splat(wc.x), acc);
            acc = __builtin_elementwise_fma(x[9],  splat(wc.y), acc);
            acc = __builtin_elementwise_fma(x[10], splat(wc.z), acc);
            acc = __builtin_elementwise_fma(x[11], splat(wc.w), acc);
            acc = __builtin_elementwise_fma(x[12], splat(wd.x), acc);
            acc = __builtin_elementwise_fma(x[13], splat(wd.y), acc);
            acc = __builtin_elementwise_fma(x[14], splat(wd.z), acc);
            acc = __builtin_elementwise_fma(x[15], splat(wd.w), acc);
            acc = __builtin_elementwise_fma(x[16], splat(we.x), acc);
            acc = __builtin_elementwise_fma(x[17], splat(we.y), acc);
            h[j] = lrelu2(acc);
        }

        // ---- 19 hidden layers: rolled, 2 per iteration (ping-pong) ----
        const float* lb = lds + LH_BASE;
        #pragma unroll 1
        for (int it = 0; it < (N_HID - 1) / 2; ++it) {
            layer10_lds(h, g, lb);
            layer10_lds(g, h, lb + 120);
            lb += 240;
        }
        layer10_lds(h, g, lb);   // layer 18

        // ---- final layer: 10 -> 1 ----
        {
            const float4* row = reinterpret_cast<const float4*>(lds + LF_BASE);
            float4 fa = row[0], fb = row[1], fc = row[2];
            v2f acc = splat(fc.z);   // bf
            acc = __builtin_elementwise_fma(g[0], splat(fa.x), acc);
            acc = __builtin_elementwise_fma(g[1], splat(fa.y), acc);
            acc = __builtin_elementwise_fma(g[2], splat(fa.z), acc);
            acc = __builtin_elementwise_fma(g[3], splat(fa.w), acc);
            acc = __builtin_elementwise_fma(g[4], splat(fb.x), acc);
            acc = __builtin_elementwise_fma(g[5], splat(fb.y), acc);
            acc = __builtin_elementwise_fma(g[6], splat(fb.z), acc);
            acc = __builtin_elementwise_fma(g[7], splat(fb.w), acc);
            acc = __builtin_elementwise_fma(g[8], splat(fc.x), acc);
            acc = __builtin_elementwise_fma(g[9], splat(fc.y), acc);
            acc = lrelu2(acc);
            float2 o; o.x = acc[0]; o.y = acc[1];
            reinterpret_cast<float2*>(out)[t] = o;
        }
    }
}

extern "C" void kernel_launch(void* const* d_in, const int* in_sizes, int n_in,
                              void* d_out, int out_size, void* d_ws, size_t ws_size,
                              hipStream_t stream) {
    const float* state  = (const float*)d_in[0];
    const float* action = (const float*)d_in[1];
    const float* W0     = (const float*)d_in[2];
    const float* b0     = (const float*)d_in[3];
    const float* Ws     = (const float*)d_in[4];
    const float* bs     = (const float*)d_in[5];
    const float* Wf     = (const float*)d_in[6];
    const float* bf     = (const float*)d_in[7];
    float* out = (float*)d_out;

    const int B = out_size;                  // [1, B] flat; B = 1048576 (even)
    const int nthreads = B / 2;              // 2 samples per thread
    const int block = 256;
    const int grid = (nthreads + block - 1) / block;
    critic_pk2_lds<<<grid, block, 0, stream>>>(state, action, W0, b0, Ws, bs, Wf, bf, out, B);
}